// Round 3
// baseline (1607.910 us; speedup 1.0000x reference)
//
#include <hip/hip_runtime.h>
#include <cstdint>

// Problem constants
#define B_  4
#define T_  2048
#define D_  1024
#define H_  16
#define DH_ 64
#define R_  8
#define M_  (B_*T_)          // 8192
#define LORA_SCALE 4.0f

typedef __attribute__((ext_vector_type(8))) short    bf16x8;
typedef __attribute__((ext_vector_type(4))) short    bf16x4;
typedef __attribute__((ext_vector_type(4))) float    f32x4;
typedef __attribute__((ext_vector_type(4))) uint32_t u32x4;

__device__ inline uint16_t f2b(float f) {             // fp32 -> bf16 RNE
    uint32_t x = __float_as_uint(f);
    return (uint16_t)((x + 0x7fffu + ((x >> 16) & 1u)) >> 16);
}
__device__ inline float b2f(uint16_t u) { return __uint_as_float(((uint32_t)u) << 16); }

__device__ __forceinline__ void gld_lds16(const uint16_t* g, uint16_t* l) {
    __builtin_amdgcn_global_load_lds(
        (const __attribute__((address_space(1))) void*)g,
        (__attribute__((address_space(3))) void*)l, 16, 0, 0);
}

// ---------------------------------------------------------------------------
// K1: cast query fp32 -> bf16   (8 elems/thread)
// ---------------------------------------------------------------------------
__global__ void cast_x_kernel(const float* __restrict__ x, uint16_t* __restrict__ out) {
    int g = blockIdx.x * 256 + threadIdx.x;
    const float4* xv = (const float4*)x;
    float4 a = xv[2 * g], b = xv[2 * g + 1];
    union { u32x4 v; uint16_t s[8]; } u;
    u.s[0] = f2b(a.x); u.s[1] = f2b(a.y); u.s[2] = f2b(a.z); u.s[3] = f2b(a.w);
    u.s[4] = f2b(b.x); u.s[5] = f2b(b.y); u.s[6] = f2b(b.z); u.s[7] = f2b(b.w);
    ((u32x4*)out)[g] = u.v;
}

// ---------------------------------------------------------------------------
// K2: build transposed bf16 weights Wt[n][k]; fold LoRA into wq/wv.
// ---------------------------------------------------------------------------
__global__ void make_wt_kernel(const float* __restrict__ wq, const float* __restrict__ wk,
                               const float* __restrict__ wv, const float* __restrict__ wo,
                               const float* __restrict__ Aq, const float* __restrict__ Bq,
                               const float* __restrict__ Av, const float* __restrict__ Bv,
                               uint16_t* __restrict__ Wt) {
    __shared__ float tile[64][65];
    int mat = blockIdx.z;
    int n0 = blockIdx.x * 64, k0 = blockIdx.y * 64;
    const float* W  = (mat == 0) ? wq : (mat == 1) ? wk : (mat == 2) ? wv : wo;
    const float* Ap = (mat == 0) ? Aq : (mat == 2) ? Av : nullptr;
    const float* Bp = (mat == 0) ? Bq : (mat == 2) ? Bv : nullptr;
    int t = threadIdx.x;
    int r = t >> 2, c0 = (t & 3) * 16;
    int k = k0 + r;
    #pragma unroll
    for (int j = 0; j < 16; j++) {
        int n = n0 + c0 + j;
        float v = W[(size_t)k * D_ + n];
        if (Ap) {
            float acc = 0.f;
            #pragma unroll
            for (int rr = 0; rr < R_; rr++) acc += Ap[k * R_ + rr] * Bp[rr * D_ + n];
            v += LORA_SCALE * acc;
        }
        tile[r][c0 + j] = v;
    }
    __syncthreads();
    int nl = t >> 2, ks = (t & 3) * 16;
    union { uint16_t s[16]; u32x4 v[2]; } uo;
    #pragma unroll
    for (int j = 0; j < 16; j++) uo.s[j] = f2b(tile[ks + j][nl]);
    uint16_t* dst = Wt + (size_t)mat * D_ * D_ + (size_t)(n0 + nl) * D_ + k0 + ks;
    *(u32x4*)&dst[0] = uo.v[0];
    *(u32x4*)&dst[8] = uo.v[1];
}

// ---------------------------------------------------------------------------
// K3/K7: C = A(MxK bf16, row-major) @ Bt(NxK bf16, row-major)^T
// Staging now via global_load_lds width=16 (m97 pattern: lane-ordered LDS dest).
// ---------------------------------------------------------------------------
template <bool OUT_F32>
__global__ __launch_bounds__(256)
void gemm_bt_kernel(const uint16_t* __restrict__ A, const uint16_t* __restrict__ Bt,
                    uint16_t* __restrict__ Cb, float* __restrict__ Cf,
                    int Mdim, int Ndim, int Kdim) {
    __shared__ uint16_t At[128 * 32];
    __shared__ uint16_t Bs[128 * 32];
    int tid = threadIdx.x;
    int wave = tid >> 6, lane = tid & 63, quad = lane >> 4, l15 = lane & 15;
    int rowBase = blockIdx.y * 128, colBase = blockIdx.x * 128;
    int wRow = (wave >> 1) * 64, wCol = (wave & 1) * 64;
    int srow0 = tid >> 2, sseg0 = (tid & 3) * 8;       // i=0
    int srow1 = (tid + 256) >> 2;                      // i=1 (same seg)
    f32x4 acc[4][4] = {};
    for (int kb = 0; kb < Kdim; kb += 32) {
        gld_lds16(&A [(size_t)(rowBase + srow0) * Kdim + kb + sseg0], &At[srow0 * 32 + sseg0]);
        gld_lds16(&A [(size_t)(rowBase + srow1) * Kdim + kb + sseg0], &At[srow1 * 32 + sseg0]);
        gld_lds16(&Bt[(size_t)(colBase + srow0) * Kdim + kb + sseg0], &Bs[srow0 * 32 + sseg0]);
        gld_lds16(&Bt[(size_t)(colBase + srow1) * Kdim + kb + sseg0], &Bs[srow1 * 32 + sseg0]);
        __syncthreads();
        bf16x8 af[4], bfr[4];
        #pragma unroll
        for (int m = 0; m < 4; m++) af[m]  = *(const bf16x8*)&At[(wRow + m * 16 + l15) * 32 + quad * 8];
        #pragma unroll
        for (int n = 0; n < 4; n++) bfr[n] = *(const bf16x8*)&Bs[(wCol + n * 16 + l15) * 32 + quad * 8];
        #pragma unroll
        for (int m = 0; m < 4; m++)
            #pragma unroll
            for (int n = 0; n < 4; n++)
                acc[m][n] = __builtin_amdgcn_mfma_f32_16x16x32_bf16(af[m], bfr[n], acc[m][n], 0, 0, 0);
        __syncthreads();
    }
    #pragma unroll
    for (int m = 0; m < 4; m++) {
        int row = rowBase + wRow + m * 16 + quad * 4;
        #pragma unroll
        for (int n = 0; n < 4; n++) {
            int col = colBase + wCol + n * 16 + l15;
            #pragma unroll
            for (int r = 0; r < 4; r++) {
                float v = acc[m][n][r];
                if (OUT_F32) Cf[(size_t)(row + r) * Ndim + col] = v;
                else         Cb[(size_t)(row + r) * Ndim + col] = f2b(v);
            }
        }
    }
}

// ---------------------------------------------------------------------------
// K4: RoPE on q,k; reshape (B,T,3D) -> (B,H,T,dh).
// ---------------------------------------------------------------------------
__global__ void rope_kernel(const uint16_t* __restrict__ qkv,
                            uint16_t* __restrict__ Qr, uint16_t* __restrict__ Kr) {
    int g = blockIdx.x * 256 + threadIdx.x;
    int i  = g & 31;
    int t  = (g >> 5) & (T_ - 1);
    int bh = g >> 16;
    int h = bh & 15, b = bh >> 4;
    size_t rowoff = ((size_t)(b * T_ + t)) * 3072 + h * 64 + 2 * i;
    uint32_t qp = *(const uint32_t*)&qkv[rowoff];
    uint32_t kp = *(const uint32_t*)&qkv[rowoff + 1024];
    float qe = b2f((uint16_t)qp), qo = b2f((uint16_t)(qp >> 16));
    float ke = b2f((uint16_t)kp), ko = b2f((uint16_t)(kp >> 16));
    float inv = exp2f(-(float)i * (13.2877123795494f / 32.f));
    float th = (float)t * inv;
    float s = sinf(th), c = cosf(th);
    uint32_t qw = (uint32_t)f2b(qe * c - qo * s) | ((uint32_t)f2b(qe * s + qo * c) << 16);
    uint32_t kw = (uint32_t)f2b(ke * c - ko * s) | ((uint32_t)f2b(ke * s + ko * c) << 16);
    size_t o = ((size_t)bh * T_ + t) * 64 + 2 * i;
    *(uint32_t*)&Qr[o] = qw;
    *(uint32_t*)&Kr[o] = kw;
}

// ---------------------------------------------------------------------------
// K5: V -> Vt (B,H,dh,T) via LDS tile transpose.
// ---------------------------------------------------------------------------
__global__ void vtrans_kernel(const uint16_t* __restrict__ qkv, uint16_t* __restrict__ Vt) {
    __shared__ uint16_t tile[32][72];
    int bh = blockIdx.y, t0 = blockIdx.x * 32;
    int b = bh >> 4, h = bh & 15;
    int tid = threadIdx.x;
    int r = tid >> 3, c8 = (tid & 7) * 8;
    *(u32x4*)&tile[r][c8] =
        *(const u32x4*)&qkv[((size_t)(b * T_ + t0 + r)) * 3072 + 2048 + h * 64 + c8];
    __syncthreads();
    int d = tid >> 2, t8 = (tid & 3) * 8;
    union { uint16_t s[8]; u32x4 v; } uu;
    #pragma unroll
    for (int j = 0; j < 8; j++) uu.s[j] = tile[t8 + j][d];
    *(u32x4*)&Vt[((size_t)bh * 64 + d) * T_ + t0 + t8] = uu.v;
}

// ---------------------------------------------------------------------------
// K6: causal flash attention, S^T orientation, LDS-staged K/V.
// grid (16, 64): block x handles q-tiles {x, 31-x} (uniform 17 chunk-128s).
// k-chunk 128 staged in LDS once per block (4 waves share); register prefetch
// of chunk c+1 overlaps compute of chunk c. P^T aliased into K's LDS region
// (barrier B1 ends all K reads before P writes; B2 ends P/V reads before the
// staged write of c+1; top-of-loop barrier makes the stage visible).
// LDS strides: K=72, V=P=136 elems -> all access patterns bank-uniform.
// ---------------------------------------------------------------------------
#define KCH  128
#define KSTR 72
#define VSTR 136
#define PSTR 136

__device__ __forceinline__ f32x4 mfma16(bf16x8 a, bf16x8 b, f32x4 c) {
    return __builtin_amdgcn_mfma_f32_16x16x32_bf16(a, b, c, 0, 0, 0);
}

template <bool MASKED>
__device__ __forceinline__ void attn_chunk_lds(
    const uint16_t* __restrict__ Kst, const uint16_t* __restrict__ Vst,
    uint16_t* __restrict__ Pw, int nact, int base_kmq,
    bf16x8 aQ0, bf16x8 aQ1, int l15, int quad,
    f32x4 (&Oacc)[4], float& mrow, float& lrow)
{
    f32x4 sacc[8];
    #pragma unroll
    for (int n = 0; n < 8; n++) {
        if (MASKED && n >= nact) continue;
        const uint16_t* kr = &Kst[(n * 16 + l15) * KSTR + quad * 8];
        bf16x8 kv0 = *(const bf16x8*)kr;
        bf16x8 kv1 = *(const bf16x8*)(kr + 32);
        f32x4 s = {};
        s = mfma16(kv0, aQ0, s);
        s = mfma16(kv1, aQ1, s);
        sacc[n] = s;
    }
    const float SC = 0.125f * 1.44269504089f;   // 1/sqrt(64) * log2(e)
    float mx = -1e30f;
    #pragma unroll
    for (int n = 0; n < 8; n++) {
        if (MASKED && n >= nact) continue;
        #pragma unroll
        for (int r = 0; r < 4; r++) {
            float v = sacc[n][r] * SC;
            if (MASKED) {
                int kmq = base_kmq + n * 16 + quad * 4 + r;   // kpos - q
                v = (kmq > 0) ? -1e30f : v;
            }
            sacc[n][r] = v;
            mx = fmaxf(mx, v);
        }
    }
    mx = fmaxf(mx, __shfl_xor(mx, 16, 64));
    mx = fmaxf(mx, __shfl_xor(mx, 32, 64));
    float mnew = fmaxf(mrow, mx);
    float alpha = exp2f(mrow - mnew);
    float sum = 0.f;
    #pragma unroll
    for (int n = 0; n < 8; n++) {
        if (MASKED && n >= nact) continue;
        #pragma unroll
        for (int r = 0; r < 4; r++) {
            float e = exp2f(sacc[n][r] - mnew);
            sacc[n][r] = e;
            sum += e;
        }
    }
    sum += __shfl_xor(sum, 16, 64);
    sum += __shfl_xor(sum, 32, 64);
    lrow = lrow * alpha + sum;
    mrow = mnew;
    #pragma unroll
    for (int m = 0; m < 4; m++)
        #pragma unroll
        for (int r = 0; r < 4; r++) Oacc[m][r] *= alpha;

    __syncthreads();                            // B1: all waves done reading Kst
    #pragma unroll
    for (int n = 0; n < 8; n++) {
        if (MASKED && n >= nact) continue;
        bf16x4 pk;
        pk[0] = (short)f2b(sacc[n][0]); pk[1] = (short)f2b(sacc[n][1]);
        pk[2] = (short)f2b(sacc[n][2]); pk[3] = (short)f2b(sacc[n][3]);
        *(bf16x4*)&Pw[l15 * PSTR + n * 16 + quad * 4] = pk;
    }
    if (MASKED && (nact & 1)) {                 // zero odd tail tile for b128 reads
        bf16x4 z = {};
        *(bf16x4*)&Pw[l15 * PSTR + nact * 16 + quad * 4] = z;
    }
    int ssact = MASKED ? ((nact + 1) >> 1) : 4;
    #pragma unroll
    for (int ss = 0; ss < 4; ss++) {
        if (MASKED && ss >= ssact) continue;
        bf16x8 bP = *(const bf16x8*)&Pw[l15 * PSTR + ss * 32 + quad * 8];
        #pragma unroll
        for (int m = 0; m < 4; m++) {
            bf16x8 aV = *(const bf16x8*)&Vst[(m * 16 + l15) * VSTR + ss * 32 + quad * 8];
            Oacc[m] = mfma16(aV, bP, Oacc[m]);
        }
    }
    __syncthreads();                            // B2: all waves done with Vst & P region
}

__global__ __launch_bounds__(256, 4)
void attn_kernel(const uint16_t* __restrict__ Qr, const uint16_t* __restrict__ Kr,
                 const uint16_t* __restrict__ Vt, uint16_t* __restrict__ Obuf) {
    __shared__ uint16_t KstS[128 * KSTR];       // 18432 B; P region aliases here
    __shared__ uint16_t VstS[64 * VSTR];        // 17408 B
    int bh = blockIdx.y;
    int b = bh >> 4, h = bh & 15;
    int tid = threadIdx.x, wave = tid >> 6, lane = tid & 63, quad = lane >> 4, l15 = lane & 15;
    const uint16_t* Qbase = Qr + (size_t)bh * T_ * 64;
    const uint16_t* Kbase = Kr + (size_t)bh * T_ * 64;
    const uint16_t* Vbase = Vt + (size_t)bh * 64 * T_;
    uint16_t* Pw = &KstS[wave * 16 * PSTR];
    int rK = tid >> 3, sK = (tid & 7) * 8;      // K staging: rows rK+j*32, 8-elem segs
    int rV = tid >> 4, sV = (tid & 15) * 8;     // V staging: rows rV+j*16
    #pragma unroll
    for (int pass = 0; pass < 2; pass++) {
        __syncthreads();                        // prev pass epilogue reads done
        int qt = pass ? (31 - (int)blockIdx.x) : (int)blockIdx.x;
        int q0w = qt * 64 + wave * 16;
        bf16x8 aQ0 = *(const bf16x8*)&Qbase[(size_t)(q0w + l15) * 64 + quad * 8];
        bf16x8 aQ1 = *(const bf16x8*)&Qbase[(size_t)(q0w + l15) * 64 + 32 + quad * 8];
        int nch = (qt >> 1) + 1;
        u32x4 gK[4], gV[4];
        #pragma unroll
        for (int j = 0; j < 4; j++)
            gK[j] = *(const u32x4*)&Kbase[(size_t)(rK + j * 32) * 64 + sK];
        #pragma unroll
        for (int j = 0; j < 4; j++)
            gV[j] = *(const u32x4*)&Vbase[(size_t)(rV + j * 16) * T_ + sV];
        #pragma unroll
        for (int j = 0; j < 4; j++) *(u32x4*)&KstS[(rK + j * 32) * KSTR + sK] = gK[j];
        #pragma unroll
        for (int j = 0; j < 4; j++) *(u32x4*)&VstS[(rV + j * 16) * VSTR + sV] = gV[j];
        f32x4 Oacc[4] = {};
        float mrow = -1e30f, lrow = 0.f;
        int klim = q0w + 15;
        for (int c = 0; c < nch; c++) {
            __syncthreads();                    // staged chunk c visible (B3 role)
            bool pre = (c + 1 < nch);
            if (pre) {
                int k0n = (c + 1) * KCH;
                #pragma unroll
                for (int j = 0; j < 4; j++)
                    gK[j] = *(const u32x4*)&Kbase[(size_t)(k0n + rK + j * 32) * 64 + sK];
                #pragma unroll
                for (int j = 0; j < 4; j++)
                    gV[j] = *(const u32x4*)&Vbase[(size_t)(rV + j * 16) * T_ + k0n + sV];
            }
            if (c == nch - 1) {
                int k0 = c * KCH;
                int nact = ((klim - k0) >> 4) + 1;
                attn_chunk_lds<true>(KstS, VstS, Pw, nact, k0 - q0w - l15,
                                     aQ0, aQ1, l15, quad, Oacc, mrow, lrow);
            } else {
                attn_chunk_lds<false>(KstS, VstS, Pw, 8, 0,
                                      aQ0, aQ1, l15, quad, Oacc, mrow, lrow);
            }
            if (pre) {
                #pragma unroll
                for (int j = 0; j < 4; j++) *(u32x4*)&KstS[(rK + j * 32) * KSTR + sK] = gK[j];
                #pragma unroll
                for (int j = 0; j < 4; j++) *(u32x4*)&VstS[(rV + j * 16) * VSTR + sV] = gV[j];
            }
        }
        // epilogue: O^T -> LDS (own P region) -> coalesced global
        float invl = 1.0f / lrow;
        float* Ow = (float*)Pw;                 // 16 q-rows x 68 f32 (272B stride)
        #pragma unroll
        for (int m = 0; m < 4; m++) {
            f32x4 o;
            #pragma unroll
            for (int r = 0; r < 4; r++) o[r] = Oacc[m][r] * invl;
            *(f32x4*)&Ow[l15 * 68 + m * 16 + quad * 4] = o;
        }
        int orow = lane >> 2, ocol = (lane & 3) * 16;
        #pragma unroll
        for (int jj = 0; jj < 4; jj++) {
            f32x4 ov = *(const f32x4*)&Ow[orow * 68 + ocol + jj * 4];
            bf16x4 ob;
            ob[0] = (short)f2b(ov[0]); ob[1] = (short)f2b(ov[1]);
            ob[2] = (short)f2b(ov[2]); ob[3] = (short)f2b(ov[3]);
            *(bf16x4*)&Obuf[((size_t)(b * T_ + qt * 64 + wave * 16 + orow)) * D_
                            + h * 64 + ocol + jj * 4] = ob;
        }
    }
}

// ---------------------------------------------------------------------------
extern "C" void kernel_launch(void* const* d_in, const int* in_sizes, int n_in,
                              void* d_out, int out_size, void* d_ws, size_t ws_size,
                              hipStream_t stream) {
    const float* query = (const float*)d_in[0];
    const float* wq = (const float*)d_in[1];
    const float* wk = (const float*)d_in[2];
    const float* wv = (const float*)d_in[3];
    const float* wo = (const float*)d_in[4];
    const float* Aq = (const float*)d_in[5];
    const float* Bq = (const float*)d_in[6];
    const float* Av = (const float*)d_in[7];
    const float* Bv = (const float*)d_in[8];
    float* out = (float*)d_out;

    const size_t MB = 1ull << 20;
    if (ws_size < 120 * MB) return;
    char* ws = (char*)d_ws;
    uint16_t* Xbf = (uint16_t*)(ws);                   // 16 MB
    uint16_t* Wt  = (uint16_t*)(ws + 16 * MB);         //  8 MB
    uint16_t* qkv = (uint16_t*)(ws + 24 * MB);         // 48 MB
    uint16_t* Qr  = (uint16_t*)(ws + 72 * MB);         // 16 MB
    uint16_t* Kr  = (uint16_t*)(ws + 88 * MB);         // 16 MB
    uint16_t* Vt  = (uint16_t*)(ws + 104 * MB);        // 16 MB
    uint16_t* Obuf = qkv;                              // reuse (dead after rope/vtrans)

    cast_x_kernel<<<4096, 256, 0, stream>>>(query, Xbf);
    make_wt_kernel<<<dim3(16, 16, 4), 256, 0, stream>>>(wq, wk, wv, wo, Aq, Bq, Av, Bv, Wt);
    gemm_bt_kernel<false><<<dim3(3072 / 128, M_ / 128), 256, 0, stream>>>(
        Xbf, Wt, qkv, nullptr, M_, 3072, D_);
    rope_kernel<<<16384, 256, 0, stream>>>(qkv, Qr, Kr);
    vtrans_kernel<<<dim3(T_ / 32, B_ * H_), 256, 0, stream>>>(qkv, Vt);
    attn_kernel<<<dim3(16, B_ * H_), 256, 0, stream>>>(Qr, Kr, Vt, Obuf);
    gemm_bt_kernel<true><<<dim3(D_ / 128, M_ / 128), 256, 0, stream>>>(
        Obuf, Wt + 3ull * D_ * D_, nullptr, out, M_, D_, D_);
}

// Round 4
// 1278.158 us; speedup vs baseline: 1.2580x; 1.2580x over previous
//
#include <hip/hip_runtime.h>
#include <cstdint>

// Problem constants
#define B_  4
#define T_  2048
#define D_  1024
#define H_  16
#define DH_ 64
#define R_  8
#define M_  (B_*T_)          // 8192
#define LORA_SCALE 4.0f

typedef __attribute__((ext_vector_type(8))) short    bf16x8;
typedef __attribute__((ext_vector_type(4))) short    bf16x4;
typedef __attribute__((ext_vector_type(4))) float    f32x4;
typedef __attribute__((ext_vector_type(4))) uint32_t u32x4;

__device__ inline uint16_t f2b(float f) {             // fp32 -> bf16 RNE
    uint32_t x = __float_as_uint(f);
    return (uint16_t)((x + 0x7fffu + ((x >> 16) & 1u)) >> 16);
}
__device__ inline float b2f(uint16_t u) { return __uint_as_float(((uint32_t)u) << 16); }

__device__ __forceinline__ void gld_lds16(const uint16_t* g, uint16_t* l) {
    __builtin_amdgcn_global_load_lds(
        (const __attribute__((address_space(1))) void*)g,
        (__attribute__((address_space(3))) void*)l, 16, 0, 0);
}

// ---------------------------------------------------------------------------
// K1: cast query fp32 -> bf16   (8 elems/thread)
// ---------------------------------------------------------------------------
__global__ void cast_x_kernel(const float* __restrict__ x, uint16_t* __restrict__ out) {
    int g = blockIdx.x * 256 + threadIdx.x;
    const float4* xv = (const float4*)x;
    float4 a = xv[2 * g], b = xv[2 * g + 1];
    union { u32x4 v; uint16_t s[8]; } u;
    u.s[0] = f2b(a.x); u.s[1] = f2b(a.y); u.s[2] = f2b(a.z); u.s[3] = f2b(a.w);
    u.s[4] = f2b(b.x); u.s[5] = f2b(b.y); u.s[6] = f2b(b.z); u.s[7] = f2b(b.w);
    ((u32x4*)out)[g] = u.v;
}

// ---------------------------------------------------------------------------
// K2: build transposed bf16 weights Wt[n][k]; fold LoRA into wq/wv.
// ---------------------------------------------------------------------------
__global__ void make_wt_kernel(const float* __restrict__ wq, const float* __restrict__ wk,
                               const float* __restrict__ wv, const float* __restrict__ wo,
                               const float* __restrict__ Aq, const float* __restrict__ Bq,
                               const float* __restrict__ Av, const float* __restrict__ Bv,
                               uint16_t* __restrict__ Wt) {
    __shared__ float tile[64][65];
    int mat = blockIdx.z;
    int n0 = blockIdx.x * 64, k0 = blockIdx.y * 64;
    const float* W  = (mat == 0) ? wq : (mat == 1) ? wk : (mat == 2) ? wv : wo;
    const float* Ap = (mat == 0) ? Aq : (mat == 2) ? Av : nullptr;
    const float* Bp = (mat == 0) ? Bq : (mat == 2) ? Bv : nullptr;
    int t = threadIdx.x;
    int r = t >> 2, c0 = (t & 3) * 16;
    int k = k0 + r;
    #pragma unroll
    for (int j = 0; j < 16; j++) {
        int n = n0 + c0 + j;
        float v = W[(size_t)k * D_ + n];
        if (Ap) {
            float acc = 0.f;
            #pragma unroll
            for (int rr = 0; rr < R_; rr++) acc += Ap[k * R_ + rr] * Bp[rr * D_ + n];
            v += LORA_SCALE * acc;
        }
        tile[r][c0 + j] = v;
    }
    __syncthreads();
    int nl = t >> 2, ks = (t & 3) * 16;
    union { uint16_t s[16]; u32x4 v[2]; } uo;
    #pragma unroll
    for (int j = 0; j < 16; j++) uo.s[j] = f2b(tile[ks + j][nl]);
    uint16_t* dst = Wt + (size_t)mat * D_ * D_ + (size_t)(n0 + nl) * D_ + k0 + ks;
    *(u32x4*)&dst[0] = uo.v[0];
    *(u32x4*)&dst[8] = uo.v[1];
}

// ---------------------------------------------------------------------------
// K3/K7: C = A(MxK bf16, row-major) @ Bt(NxK bf16, row-major)^T
// Staging via global_load_lds width=16 (lane-ordered LDS dest).
// ---------------------------------------------------------------------------
template <bool OUT_F32>
__global__ __launch_bounds__(256)
void gemm_bt_kernel(const uint16_t* __restrict__ A, const uint16_t* __restrict__ Bt,
                    uint16_t* __restrict__ Cb, float* __restrict__ Cf,
                    int Mdim, int Ndim, int Kdim) {
    __shared__ uint16_t At[128 * 32];
    __shared__ uint16_t Bs[128 * 32];
    int tid = threadIdx.x;
    int wave = tid >> 6, lane = tid & 63, quad = lane >> 4, l15 = lane & 15;
    int rowBase = blockIdx.y * 128, colBase = blockIdx.x * 128;
    int wRow = (wave >> 1) * 64, wCol = (wave & 1) * 64;
    int srow0 = tid >> 2, sseg0 = (tid & 3) * 8;
    int srow1 = (tid + 256) >> 2;
    f32x4 acc[4][4] = {};
    for (int kb = 0; kb < Kdim; kb += 32) {
        gld_lds16(&A [(size_t)(rowBase + srow0) * Kdim + kb + sseg0], &At[srow0 * 32 + sseg0]);
        gld_lds16(&A [(size_t)(rowBase + srow1) * Kdim + kb + sseg0], &At[srow1 * 32 + sseg0]);
        gld_lds16(&Bt[(size_t)(colBase + srow0) * Kdim + kb + sseg0], &Bs[srow0 * 32 + sseg0]);
        gld_lds16(&Bt[(size_t)(colBase + srow1) * Kdim + kb + sseg0], &Bs[srow1 * 32 + sseg0]);
        __syncthreads();
        bf16x8 af[4], bfr[4];
        #pragma unroll
        for (int m = 0; m < 4; m++) af[m]  = *(const bf16x8*)&At[(wRow + m * 16 + l15) * 32 + quad * 8];
        #pragma unroll
        for (int n = 0; n < 4; n++) bfr[n] = *(const bf16x8*)&Bs[(wCol + n * 16 + l15) * 32 + quad * 8];
        #pragma unroll
        for (int m = 0; m < 4; m++)
            #pragma unroll
            for (int n = 0; n < 4; n++)
                acc[m][n] = __builtin_amdgcn_mfma_f32_16x16x32_bf16(af[m], bfr[n], acc[m][n], 0, 0, 0);
        __syncthreads();
    }
    #pragma unroll
    for (int m = 0; m < 4; m++) {
        int row = rowBase + wRow + m * 16 + quad * 4;
        #pragma unroll
        for (int n = 0; n < 4; n++) {
            int col = colBase + wCol + n * 16 + l15;
            #pragma unroll
            for (int r = 0; r < 4; r++) {
                float v = acc[m][n][r];
                if (OUT_F32) Cf[(size_t)(row + r) * Ndim + col] = v;
                else         Cb[(size_t)(row + r) * Ndim + col] = f2b(v);
            }
        }
    }
}

// ---------------------------------------------------------------------------
// K4: RoPE on q,k; reshape (B,T,3D) -> (B,H,T,dh).
// ---------------------------------------------------------------------------
__global__ void rope_kernel(const uint16_t* __restrict__ qkv,
                            uint16_t* __restrict__ Qr, uint16_t* __restrict__ Kr) {
    int g = blockIdx.x * 256 + threadIdx.x;
    int i  = g & 31;
    int t  = (g >> 5) & (T_ - 1);
    int bh = g >> 16;
    int h = bh & 15, b = bh >> 4;
    size_t rowoff = ((size_t)(b * T_ + t)) * 3072 + h * 64 + 2 * i;
    uint32_t qp = *(const uint32_t*)&qkv[rowoff];
    uint32_t kp = *(const uint32_t*)&qkv[rowoff + 1024];
    float qe = b2f((uint16_t)qp), qo = b2f((uint16_t)(qp >> 16));
    float ke = b2f((uint16_t)kp), ko = b2f((uint16_t)(kp >> 16));
    float inv = exp2f(-(float)i * (13.2877123795494f / 32.f));
    float th = (float)t * inv;
    float s = sinf(th), c = cosf(th);
    uint32_t qw = (uint32_t)f2b(qe * c - qo * s) | ((uint32_t)f2b(qe * s + qo * c) << 16);
    uint32_t kw = (uint32_t)f2b(ke * c - ko * s) | ((uint32_t)f2b(ke * s + ko * c) << 16);
    size_t o = ((size_t)bh * T_ + t) * 64 + 2 * i;
    *(uint32_t*)&Qr[o] = qw;
    *(uint32_t*)&Kr[o] = kw;
}

// ---------------------------------------------------------------------------
// K5: V -> Vt (B,H,dh,T) via LDS tile transpose.
// ---------------------------------------------------------------------------
__global__ void vtrans_kernel(const uint16_t* __restrict__ qkv, uint16_t* __restrict__ Vt) {
    __shared__ uint16_t tile[32][72];
    int bh = blockIdx.y, t0 = blockIdx.x * 32;
    int b = bh >> 4, h = bh & 15;
    int tid = threadIdx.x;
    int r = tid >> 3, c8 = (tid & 7) * 8;
    *(u32x4*)&tile[r][c8] =
        *(const u32x4*)&qkv[((size_t)(b * T_ + t0 + r)) * 3072 + 2048 + h * 64 + c8];
    __syncthreads();
    int d = tid >> 2, t8 = (tid & 3) * 8;
    union { uint16_t s[8]; u32x4 v; } uu;
    #pragma unroll
    for (int j = 0; j < 8; j++) uu.s[j] = tile[t8 + j][d];
    *(u32x4*)&Vt[((size_t)bh * 64 + d) * T_ + t0 + t8] = uu.v;
}

// ---------------------------------------------------------------------------
// K6: causal flash attention, S^T orientation, LDS-staged K/V (transient regs,
// NO held prefetch -- round-3's held prefetch spilled to scratch: 5.2 GB HBM
// writes). XCD swizzle: all 16 q-blocks of one bh on one XCD for L2 locality.
// Per chunk: barrier(a) [safe to overwrite], stage 8xb128 -> ds_write,
// barrier(b) [visible], QK+softmax, barrier(c) [K reads done], P-write into
// K-region alias, PV. LDS strides K=72, V=P=136 keep accesses bank-uniform.
// ---------------------------------------------------------------------------
#define KCH  128
#define KSTR 72
#define VSTR 136
#define PSTR 136

__device__ __forceinline__ f32x4 mfma16(bf16x8 a, bf16x8 b, f32x4 c) {
    return __builtin_amdgcn_mfma_f32_16x16x32_bf16(a, b, c, 0, 0, 0);
}

template <bool MASKED>
__device__ __forceinline__ void attn_chunk_lds(
    const uint16_t* __restrict__ Kst, const uint16_t* __restrict__ Vst,
    uint16_t* __restrict__ Pw, int nact, int base_kmq,
    bf16x8 aQ0, bf16x8 aQ1, int l15, int quad,
    f32x4 (&Oacc)[4], float& mrow, float& lrow)
{
    f32x4 sacc[8];
    #pragma unroll
    for (int n = 0; n < 8; n++) {
        if (MASKED && n >= nact) continue;
        const uint16_t* kr = &Kst[(n * 16 + l15) * KSTR + quad * 8];
        bf16x8 kv0 = *(const bf16x8*)kr;
        bf16x8 kv1 = *(const bf16x8*)(kr + 32);
        f32x4 s = {};
        s = mfma16(kv0, aQ0, s);
        s = mfma16(kv1, aQ1, s);
        sacc[n] = s;
    }
    const float SC = 0.125f * 1.44269504089f;   // 1/sqrt(64) * log2(e)
    float mx = -1e30f;
    #pragma unroll
    for (int n = 0; n < 8; n++) {
        if (MASKED && n >= nact) continue;
        #pragma unroll
        for (int r = 0; r < 4; r++) {
            float v = sacc[n][r] * SC;
            if (MASKED) {
                int kmq = base_kmq + n * 16 + quad * 4 + r;   // kpos - q
                v = (kmq > 0) ? -1e30f : v;
            }
            sacc[n][r] = v;
            mx = fmaxf(mx, v);
        }
    }
    mx = fmaxf(mx, __shfl_xor(mx, 16, 64));
    mx = fmaxf(mx, __shfl_xor(mx, 32, 64));
    float mnew = fmaxf(mrow, mx);
    float alpha = exp2f(mrow - mnew);
    float sum = 0.f;
    #pragma unroll
    for (int n = 0; n < 8; n++) {
        if (MASKED && n >= nact) continue;
        #pragma unroll
        for (int r = 0; r < 4; r++) {
            float e = exp2f(sacc[n][r] - mnew);
            sacc[n][r] = e;
            sum += e;
        }
    }
    sum += __shfl_xor(sum, 16, 64);
    sum += __shfl_xor(sum, 32, 64);
    lrow = lrow * alpha + sum;
    mrow = mnew;
    #pragma unroll
    for (int m = 0; m < 4; m++)
        #pragma unroll
        for (int r = 0; r < 4; r++) Oacc[m][r] *= alpha;

    __syncthreads();                            // (c): all waves done reading Kst
    #pragma unroll
    for (int n = 0; n < 8; n++) {
        if (MASKED && n >= nact) continue;
        bf16x4 pk;
        pk[0] = (short)f2b(sacc[n][0]); pk[1] = (short)f2b(sacc[n][1]);
        pk[2] = (short)f2b(sacc[n][2]); pk[3] = (short)f2b(sacc[n][3]);
        *(bf16x4*)&Pw[l15 * PSTR + n * 16 + quad * 4] = pk;
    }
    if (MASKED && (nact & 1)) {                 // zero odd tail tile for b128 reads
        bf16x4 z = {};
        *(bf16x4*)&Pw[l15 * PSTR + nact * 16 + quad * 4] = z;
    }
    int ssact = MASKED ? ((nact + 1) >> 1) : 4;
    #pragma unroll
    for (int ss = 0; ss < 4; ss++) {
        if (MASKED && ss >= ssact) continue;
        bf16x8 bP = *(const bf16x8*)&Pw[l15 * PSTR + ss * 32 + quad * 8];
        #pragma unroll
        for (int m = 0; m < 4; m++) {
            bf16x8 aV = *(const bf16x8*)&Vst[(m * 16 + l15) * VSTR + ss * 32 + quad * 8];
            Oacc[m] = mfma16(aV, bP, Oacc[m]);
        }
    }
}

__global__ __launch_bounds__(256, 4)
void attn_kernel(const uint16_t* __restrict__ Qr, const uint16_t* __restrict__ Kr,
                 const uint16_t* __restrict__ Vt, uint16_t* __restrict__ Obuf) {
    __shared__ uint16_t KstS[128 * KSTR];       // 18432 B; P slabs alias here
    __shared__ uint16_t VstS[64 * VSTR];        // 17408 B
    // XCD swizzle: id = xcd + 8*(bh_low + 8*x)  -> bh's 16 blocks on one XCD
    int id  = blockIdx.x;
    int xcd = id & 7, grp = id >> 3;
    int bh  = xcd * 8 + (grp & 7);
    int qx  = grp >> 3;                         // 0..15
    int b = bh >> 4, h = bh & 15;
    int tid = threadIdx.x, wave = tid >> 6, lane = tid & 63, quad = lane >> 4, l15 = lane & 15;
    const uint16_t* Qbase = Qr + (size_t)bh * T_ * 64;
    const uint16_t* Kbase = Kr + (size_t)bh * T_ * 64;
    const uint16_t* Vbase = Vt + (size_t)bh * 64 * T_;
    uint16_t* Pw = &KstS[wave * 16 * PSTR];
    int rK = tid >> 3, sK = (tid & 7) * 8;      // K staging: rows rK+j*32
    int rV = tid >> 4, sV = (tid & 15) * 8;     // V staging: rows rV+j*16
    #pragma unroll
    for (int pass = 0; pass < 2; pass++) {
        int qt = pass ? (31 - qx) : qx;
        int q0w = qt * 64 + wave * 16;
        bf16x8 aQ0 = *(const bf16x8*)&Qbase[(size_t)(q0w + l15) * 64 + quad * 8];
        bf16x8 aQ1 = *(const bf16x8*)&Qbase[(size_t)(q0w + l15) * 64 + 32 + quad * 8];
        f32x4 Oacc[4] = {};
        float mrow = -1e30f, lrow = 0.f;
        int nch = (qt >> 1) + 1;
        int klim = q0w + 15;
        for (int c = 0; c < nch; c++) {
            int k0 = c * KCH;
            __syncthreads();                    // (a) prev chunk/pass LDS reads done
            {                                   // transient stage: load -> ds_write, regs die here
                u32x4 tK[4], tV[4];
                #pragma unroll
                for (int j = 0; j < 4; j++)
                    tK[j] = *(const u32x4*)&Kbase[(size_t)(k0 + rK + j * 32) * 64 + sK];
                #pragma unroll
                for (int j = 0; j < 4; j++)
                    tV[j] = *(const u32x4*)&Vbase[(size_t)(rV + j * 16) * T_ + k0 + sV];
                #pragma unroll
                for (int j = 0; j < 4; j++) *(u32x4*)&KstS[(rK + j * 32) * KSTR + sK] = tK[j];
                #pragma unroll
                for (int j = 0; j < 4; j++) *(u32x4*)&VstS[(rV + j * 16) * VSTR + sV] = tV[j];
            }
            __syncthreads();                    // (b) stage visible
            if (c == nch - 1) {
                int nact = ((klim - k0) >> 4) + 1;
                attn_chunk_lds<true>(KstS, VstS, Pw, nact, k0 - q0w - l15,
                                     aQ0, aQ1, l15, quad, Oacc, mrow, lrow);
            } else {
                attn_chunk_lds<false>(KstS, VstS, Pw, 8, 0,
                                      aQ0, aQ1, l15, quad, Oacc, mrow, lrow);
            }
        }
        // epilogue: O^T -> own P slab (wave-private) -> coalesced global
        float invl = 1.0f / lrow;
        float* Ow = (float*)Pw;                 // 16 q-rows x 68 f32
        #pragma unroll
        for (int m = 0; m < 4; m++) {
            f32x4 o;
            #pragma unroll
            for (int r = 0; r < 4; r++) o[r] = Oacc[m][r] * invl;
            *(f32x4*)&Ow[l15 * 68 + m * 16 + quad * 4] = o;
        }
        int orow = lane >> 2, ocol = (lane & 3) * 16;
        #pragma unroll
        for (int jj = 0; jj < 4; jj++) {
            f32x4 ov = *(const f32x4*)&Ow[orow * 68 + ocol + jj * 4];
            bf16x4 ob;
            ob[0] = (short)f2b(ov[0]); ob[1] = (short)f2b(ov[1]);
            ob[2] = (short)f2b(ov[2]); ob[3] = (short)f2b(ov[3]);
            *(bf16x4*)&Obuf[((size_t)(b * T_ + qt * 64 + wave * 16 + orow)) * D_
                            + h * 64 + ocol + jj * 4] = ob;
        }
    }
}

// ---------------------------------------------------------------------------
extern "C" void kernel_launch(void* const* d_in, const int* in_sizes, int n_in,
                              void* d_out, int out_size, void* d_ws, size_t ws_size,
                              hipStream_t stream) {
    const float* query = (const float*)d_in[0];
    const float* wq = (const float*)d_in[1];
    const float* wk = (const float*)d_in[2];
    const float* wv = (const float*)d_in[3];
    const float* wo = (const float*)d_in[4];
    const float* Aq = (const float*)d_in[5];
    const float* Bq = (const float*)d_in[6];
    const float* Av = (const float*)d_in[7];
    const float* Bv = (const float*)d_in[8];
    float* out = (float*)d_out;

    const size_t MB = 1ull << 20;
    if (ws_size < 120 * MB) return;
    char* ws = (char*)d_ws;
    uint16_t* Xbf = (uint16_t*)(ws);                   // 16 MB
    uint16_t* Wt  = (uint16_t*)(ws + 16 * MB);         //  8 MB
    uint16_t* qkv = (uint16_t*)(ws + 24 * MB);         // 48 MB
    uint16_t* Qr  = (uint16_t*)(ws + 72 * MB);         // 16 MB
    uint16_t* Kr  = (uint16_t*)(ws + 88 * MB);         // 16 MB
    uint16_t* Vt  = (uint16_t*)(ws + 104 * MB);        // 16 MB
    uint16_t* Obuf = qkv;                              // reuse (dead after rope/vtrans)

    cast_x_kernel<<<4096, 256, 0, stream>>>(query, Xbf);
    make_wt_kernel<<<dim3(16, 16, 4), 256, 0, stream>>>(wq, wk, wv, wo, Aq, Bq, Av, Bv, Wt);
    gemm_bt_kernel<false><<<dim3(3072 / 128, M_ / 128), 256, 0, stream>>>(
        Xbf, Wt, qkv, nullptr, M_, 3072, D_);
    rope_kernel<<<16384, 256, 0, stream>>>(qkv, Qr, Kr);
    vtrans_kernel<<<dim3(T_ / 32, B_ * H_), 256, 0, stream>>>(qkv, Vt);
    attn_kernel<<<1024, 256, 0, stream>>>(Qr, Kr, Vt, Obuf);
    gemm_bt_kernel<true><<<dim3(D_ / 128, M_ / 128), 256, 0, stream>>>(
        Obuf, Wt + 3ull * D_ * D_, nullptr, out, M_, D_, D_);
}

// Round 6
// 471.209 us; speedup vs baseline: 3.4123x; 2.7125x over previous
//
#include <hip/hip_runtime.h>
#include <cstdint>

// Problem constants
#define B_  4
#define T_  2048
#define D_  1024
#define H_  16
#define DH_ 64
#define R_  8
#define M_  (B_*T_)          // 8192
#define LORA_SCALE 4.0f

typedef __attribute__((ext_vector_type(8))) short    bf16x8;
typedef __attribute__((ext_vector_type(4))) short    bf16x4;
typedef __attribute__((ext_vector_type(4))) float    f32x4;
typedef __attribute__((ext_vector_type(4))) uint32_t u32x4;

__device__ inline uint16_t f2b(float f) {             // fp32 -> bf16 RNE
    uint32_t x = __float_as_uint(f);
    return (uint16_t)((x + 0x7fffu + ((x >> 16) & 1u)) >> 16);
}
__device__ inline float b2f(uint16_t u) { return __uint_as_float(((uint32_t)u) << 16); }

__device__ __forceinline__ void gld_lds16(const uint16_t* g, uint16_t* l) {
    __builtin_amdgcn_global_load_lds(
        (const __attribute__((address_space(1))) void*)g,
        (__attribute__((address_space(3))) void*)l, 16, 0, 0);
}

// ---------------------------------------------------------------------------
// K1: cast query fp32 -> bf16   (8 elems/thread)
// ---------------------------------------------------------------------------
__global__ void cast_x_kernel(const float* __restrict__ x, uint16_t* __restrict__ out) {
    int g = blockIdx.x * 256 + threadIdx.x;
    const float4* xv = (const float4*)x;
    float4 a = xv[2 * g], b = xv[2 * g + 1];
    union { u32x4 v; uint16_t s[8]; } u;
    u.s[0] = f2b(a.x); u.s[1] = f2b(a.y); u.s[2] = f2b(a.z); u.s[3] = f2b(a.w);
    u.s[4] = f2b(b.x); u.s[5] = f2b(b.y); u.s[6] = f2b(b.z); u.s[7] = f2b(b.w);
    ((u32x4*)out)[g] = u.v;
}

// ---------------------------------------------------------------------------
// K2: build transposed bf16 weights Wt[n][k]; fold LoRA into wq/wv.
// ---------------------------------------------------------------------------
__global__ void make_wt_kernel(const float* __restrict__ wq, const float* __restrict__ wk,
                               const float* __restrict__ wv, const float* __restrict__ wo,
                               const float* __restrict__ Aq, const float* __restrict__ Bq,
                               const float* __restrict__ Av, const float* __restrict__ Bv,
                               uint16_t* __restrict__ Wt) {
    __shared__ float tile[64][65];
    int mat = blockIdx.z;
    int n0 = blockIdx.x * 64, k0 = blockIdx.y * 64;
    const float* W  = (mat == 0) ? wq : (mat == 1) ? wk : (mat == 2) ? wv : wo;
    const float* Ap = (mat == 0) ? Aq : (mat == 2) ? Av : nullptr;
    const float* Bp = (mat == 0) ? Bq : (mat == 2) ? Bv : nullptr;
    int t = threadIdx.x;
    int r = t >> 2, c0 = (t & 3) * 16;
    int k = k0 + r;
    #pragma unroll
    for (int j = 0; j < 16; j++) {
        int n = n0 + c0 + j;
        float v = W[(size_t)k * D_ + n];
        if (Ap) {
            float acc = 0.f;
            #pragma unroll
            for (int rr = 0; rr < R_; rr++) acc += Ap[k * R_ + rr] * Bp[rr * D_ + n];
            v += LORA_SCALE * acc;
        }
        tile[r][c0 + j] = v;
    }
    __syncthreads();
    int nl = t >> 2, ks = (t & 3) * 16;
    union { uint16_t s[16]; u32x4 v[2]; } uo;
    #pragma unroll
    for (int j = 0; j < 16; j++) uo.s[j] = f2b(tile[ks + j][nl]);
    uint16_t* dst = Wt + (size_t)mat * D_ * D_ + (size_t)(n0 + nl) * D_ + k0 + ks;
    *(u32x4*)&dst[0] = uo.v[0];
    *(u32x4*)&dst[8] = uo.v[1];
}

// ---------------------------------------------------------------------------
// K3/K7: C = A(MxK bf16, row-major) @ Bt(NxK bf16, row-major)^T
// Staging via global_load_lds width=16 (lane-ordered, the ONLY supported DMA
// pattern: global base+lane*16 -> LDS base+lane*16). Proven in rounds 3/4.
// ---------------------------------------------------------------------------
template <bool OUT_F32>
__global__ __launch_bounds__(256)
void gemm_bt_kernel(const uint16_t* __restrict__ A, const uint16_t* __restrict__ Bt,
                    uint16_t* __restrict__ Cb, float* __restrict__ Cf,
                    int Mdim, int Ndim, int Kdim) {
    __shared__ uint16_t At[128 * 32];
    __shared__ uint16_t Bs[128 * 32];
    int tid = threadIdx.x;
    int wave = tid >> 6, lane = tid & 63, quad = lane >> 4, l15 = lane & 15;
    int rowBase = blockIdx.y * 128, colBase = blockIdx.x * 128;
    int wRow = (wave >> 1) * 64, wCol = (wave & 1) * 64;
    int srow0 = tid >> 2, sseg0 = (tid & 3) * 8;
    int srow1 = (tid + 256) >> 2;
    f32x4 acc[4][4] = {};
    for (int kb = 0; kb < Kdim; kb += 32) {
        gld_lds16(&A [(size_t)(rowBase + srow0) * Kdim + kb + sseg0], &At[srow0 * 32 + sseg0]);
        gld_lds16(&A [(size_t)(rowBase + srow1) * Kdim + kb + sseg0], &At[srow1 * 32 + sseg0]);
        gld_lds16(&Bt[(size_t)(colBase + srow0) * Kdim + kb + sseg0], &Bs[srow0 * 32 + sseg0]);
        gld_lds16(&Bt[(size_t)(colBase + srow1) * Kdim + kb + sseg0], &Bs[srow1 * 32 + sseg0]);
        __syncthreads();
        bf16x8 af[4], bfr[4];
        #pragma unroll
        for (int m = 0; m < 4; m++) af[m]  = *(const bf16x8*)&At[(wRow + m * 16 + l15) * 32 + quad * 8];
        #pragma unroll
        for (int n = 0; n < 4; n++) bfr[n] = *(const bf16x8*)&Bs[(wCol + n * 16 + l15) * 32 + quad * 8];
        #pragma unroll
        for (int m = 0; m < 4; m++)
            #pragma unroll
            for (int n = 0; n < 4; n++)
                acc[m][n] = __builtin_amdgcn_mfma_f32_16x16x32_bf16(af[m], bfr[n], acc[m][n], 0, 0, 0);
        __syncthreads();
    }
    #pragma unroll
    for (int m = 0; m < 4; m++) {
        int row = rowBase + wRow + m * 16 + quad * 4;
        #pragma unroll
        for (int n = 0; n < 4; n++) {
            int col = colBase + wCol + n * 16 + l15;
            #pragma unroll
            for (int r = 0; r < 4; r++) {
                float v = acc[m][n][r];
                if (OUT_F32) Cf[(size_t)(row + r) * Ndim + col] = v;
                else         Cb[(size_t)(row + r) * Ndim + col] = f2b(v);
            }
        }
    }
}

// ---------------------------------------------------------------------------
// K4: RoPE on q,k; reshape (B,T,3D) -> (B,H,T,dh).
// ---------------------------------------------------------------------------
__global__ void rope_kernel(const uint16_t* __restrict__ qkv,
                            uint16_t* __restrict__ Qr, uint16_t* __restrict__ Kr) {
    int g = blockIdx.x * 256 + threadIdx.x;
    int i  = g & 31;
    int t  = (g >> 5) & (T_ - 1);
    int bh = g >> 16;
    int h = bh & 15, b = bh >> 4;
    size_t rowoff = ((size_t)(b * T_ + t)) * 3072 + h * 64 + 2 * i;
    uint32_t qp = *(const uint32_t*)&qkv[rowoff];
    uint32_t kp = *(const uint32_t*)&qkv[rowoff + 1024];
    float qe = b2f((uint16_t)qp), qo = b2f((uint16_t)(qp >> 16));
    float ke = b2f((uint16_t)kp), ko = b2f((uint16_t)(kp >> 16));
    float inv = exp2f(-(float)i * (13.2877123795494f / 32.f));
    float th = (float)t * inv;
    float s = sinf(th), c = cosf(th);
    uint32_t qw = (uint32_t)f2b(qe * c - qo * s) | ((uint32_t)f2b(qe * s + qo * c) << 16);
    uint32_t kw = (uint32_t)f2b(ke * c - ko * s) | ((uint32_t)f2b(ke * s + ko * c) << 16);
    size_t o = ((size_t)bh * T_ + t) * 64 + 2 * i;
    *(uint32_t*)&Qr[o] = qw;
    *(uint32_t*)&Kr[o] = kw;
}

// ---------------------------------------------------------------------------
// K5: V -> Vt (B,H,dh,T) via LDS tile transpose.
// ---------------------------------------------------------------------------
__global__ void vtrans_kernel(const uint16_t* __restrict__ qkv, uint16_t* __restrict__ Vt) {
    __shared__ uint16_t tile[32][72];
    int bh = blockIdx.y, t0 = blockIdx.x * 32;
    int b = bh >> 4, h = bh & 15;
    int tid = threadIdx.x;
    int r = tid >> 3, c8 = (tid & 7) * 8;
    *(u32x4*)&tile[r][c8] =
        *(const u32x4*)&qkv[((size_t)(b * T_ + t0 + r)) * 3072 + 2048 + h * 64 + c8];
    __syncthreads();
    int d = tid >> 2, t8 = (tid & 3) * 8;
    union { uint16_t s[8]; u32x4 v; } uu;
    #pragma unroll
    for (int j = 0; j < 8; j++) uu.s[j] = tile[t8 + j][d];
    *(u32x4*)&Vt[((size_t)bh * 64 + d) * T_ + t0 + t8] = uu.v;
}

// ---------------------------------------------------------------------------
// K6: causal flash attention, S^T orientation -- EXACT round-2 compute path
// (known correct, WRITE_SIZE == true output, no spill) + XCD swizzle so each
// bh's K/V (512 KB) is re-read by 16 blocks all resident on ONE XCD:
// 8 bh/XCD * 512 KB = 4 MB = L2 capacity -> K/V re-reads become L2 hits
// (~250 cy) instead of HBM misses (~900 cy). This attacks the measured
// limiter: outstanding-load-limited latency at VGPR=64.
// ---------------------------------------------------------------------------
#define PSTRIDE 264   // bf16 elems per P row: 528B, 16B-aligned, bank-spread

__device__ __forceinline__ f32x4 mfma16(bf16x8 a, bf16x8 b, f32x4 c) {
    return __builtin_amdgcn_mfma_f32_16x16x32_bf16(a, b, c, 0, 0, 0);
}

template <bool MASKED>
__device__ __forceinline__ void attn_chunk(
    const uint16_t* __restrict__ Kb, const uint16_t* __restrict__ Vb,
    uint16_t* __restrict__ Pw, int k0, int nact, int base_kmq,
    bf16x8 aQ0, bf16x8 aQ1, int l15, int quad,
    f32x4 (&Oacc)[4], float& mrow, float& lrow)
{
    f32x4 sacc[16];
    #pragma unroll
    for (int n = 0; n < 16; n++) {
        if (MASKED && n >= nact) continue;
        const uint16_t* kr = &Kb[(size_t)(k0 + n * 16 + l15) * 64 + quad * 8];
        bf16x8 kv0 = *(const bf16x8*)kr;
        bf16x8 kv1 = *(const bf16x8*)(kr + 32);
        f32x4 s = {};
        s = mfma16(kv0, aQ0, s);
        s = mfma16(kv1, aQ1, s);
        sacc[n] = s;
    }
    const float SC = 0.125f * 1.44269504089f;   // 1/sqrt(64) * log2(e)
    float mx = -1e30f;
    #pragma unroll
    for (int n = 0; n < 16; n++) {
        if (MASKED && n >= nact) continue;
        #pragma unroll
        for (int r = 0; r < 4; r++) {
            float v = sacc[n][r] * SC;
            if (MASKED) {
                int kmq = base_kmq + n * 16 + quad * 4 + r;   // kpos - q
                v = (kmq > 0) ? -1e30f : v;
            }
            sacc[n][r] = v;
            mx = fmaxf(mx, v);
        }
    }
    mx = fmaxf(mx, __shfl_xor(mx, 16, 64));
    mx = fmaxf(mx, __shfl_xor(mx, 32, 64));
    float mnew = fmaxf(mrow, mx);
    float alpha = exp2f(mrow - mnew);
    float sum = 0.f;
    #pragma unroll
    for (int n = 0; n < 16; n++) {
        if (MASKED && n >= nact) continue;
        #pragma unroll
        for (int r = 0; r < 4; r++) {
            float e = exp2f(sacc[n][r] - mnew);
            sacc[n][r] = e;
            sum += e;
        }
    }
    sum += __shfl_xor(sum, 16, 64);
    sum += __shfl_xor(sum, 32, 64);
    lrow = lrow * alpha + sum;
    mrow = mnew;
    #pragma unroll
    for (int m = 0; m < 4; m++)
        #pragma unroll
        for (int r = 0; r < 4; r++) Oacc[m][r] *= alpha;
    // P^T -> LDS: row q=l15, 4 consecutive kpos per lane -> b64
    #pragma unroll
    for (int n = 0; n < 16; n++) {
        if (MASKED && n >= nact) continue;
        bf16x4 pk;
        pk[0] = (short)f2b(sacc[n][0]); pk[1] = (short)f2b(sacc[n][1]);
        pk[2] = (short)f2b(sacc[n][2]); pk[3] = (short)f2b(sacc[n][3]);
        *(bf16x4*)&Pw[l15 * PSTRIDE + n * 16 + quad * 4] = pk;
    }
    if (MASKED && (nact & 1)) {                 // zero odd tail tile for PV b128 reads
        bf16x4 z = {};
        *(bf16x4*)&Pw[l15 * PSTRIDE + nact * 16 + quad * 4] = z;
    }
    int ssact = MASKED ? ((nact + 1) >> 1) : 8;
    #pragma unroll
    for (int ss = 0; ss < 8; ss++) {
        if (MASKED && ss >= ssact) continue;
        bf16x8 bP = *(const bf16x8*)&Pw[l15 * PSTRIDE + ss * 32 + quad * 8];
        #pragma unroll
        for (int m = 0; m < 4; m++) {
            bf16x8 aV = *(const bf16x8*)&Vb[(size_t)(m * 16 + l15) * T_ + k0 + ss * 32 + quad * 8];
            Oacc[m] = mfma16(aV, bP, Oacc[m]);
        }
    }
}

__global__ __launch_bounds__(256, 4)
void attn_kernel(const uint16_t* __restrict__ Qr, const uint16_t* __restrict__ Kr,
                 const uint16_t* __restrict__ Vt, uint16_t* __restrict__ Obuf) {
    __shared__ uint16_t Pl[4][16 * PSTRIDE];    // 33792 B
    // XCD swizzle: id = xcd + 8*(bh_low + 8*qx) -> bh's 16 q-blocks on one XCD.
    // Per XCD: 8 bh * (K+V = 512 KB) = 4 MB = L2 capacity.
    int id  = blockIdx.x;
    int xcd = id & 7, grp = id >> 3;
    int bh  = xcd * 8 + (grp & 7);
    int qx  = grp >> 3;                         // 0..15
    int b = bh >> 4, h = bh & 15;
    int tid = threadIdx.x, wave = tid >> 6, lane = tid & 63, quad = lane >> 4, l15 = lane & 15;
    const uint16_t* Qbase = Qr + (size_t)bh * T_ * 64;
    const uint16_t* Kbase = Kr + (size_t)bh * T_ * 64;
    const uint16_t* Vbase = Vt + (size_t)bh * 64 * T_;
    uint16_t* Pw = &Pl[wave][0];
    #pragma unroll
    for (int pass = 0; pass < 2; pass++) {
        int qt = pass ? (31 - qx) : qx;
        int q0w = qt * 64 + wave * 16;
        bf16x8 aQ0 = *(const bf16x8*)&Qbase[(size_t)(q0w + l15) * 64 + quad * 8];
        bf16x8 aQ1 = *(const bf16x8*)&Qbase[(size_t)(q0w + l15) * 64 + 32 + quad * 8];
        f32x4 Oacc[4] = {};
        float mrow = -1e30f, lrow = 0.f;
        int niter = (qt >> 2) + 1;
        int klim = q0w + 15;
        for (int it = 0; it < niter - 1; it++)
            attn_chunk<false>(Kbase, Vbase, Pw, it * 256, 16, 0,
                              aQ0, aQ1, l15, quad, Oacc, mrow, lrow);
        {
            int k0 = (niter - 1) * 256;
            int nact = ((klim - k0) >> 4) + 1;
            attn_chunk<true>(Kbase, Vbase, Pw, k0, nact, k0 - q0w - l15,
                             aQ0, aQ1, l15, quad, Oacc, mrow, lrow);
        }
        // epilogue: O^T (row=dh=m*16+quad*4+r, col=q=l15) -> LDS -> coalesced global
        float invl = 1.0f / lrow;
        float* Ow = (float*)Pw;                 // 16 q-rows x 68 f32 (272B stride)
        #pragma unroll
        for (int m = 0; m < 4; m++) {
            f32x4 o;
            #pragma unroll
            for (int r = 0; r < 4; r++) o[r] = Oacc[m][r] * invl;
            *(f32x4*)&Ow[l15 * 68 + m * 16 + quad * 4] = o;
        }
        int orow = lane >> 2, ocol = (lane & 3) * 16;
        #pragma unroll
        for (int jj = 0; jj < 4; jj++) {
            f32x4 ov = *(const f32x4*)&Ow[orow * 68 + ocol + jj * 4];
            bf16x4 ob;
            ob[0] = (short)f2b(ov[0]); ob[1] = (short)f2b(ov[1]);
            ob[2] = (short)f2b(ov[2]); ob[3] = (short)f2b(ov[3]);
            *(bf16x4*)&Obuf[((size_t)(b * T_ + qt * 64 + wave * 16 + orow)) * D_
                            + h * 64 + ocol + jj * 4] = ob;
        }
        __syncthreads();                        // Pw (LDS) reads done before next pass reuses
    }
}

// ---------------------------------------------------------------------------
extern "C" void kernel_launch(void* const* d_in, const int* in_sizes, int n_in,
                              void* d_out, int out_size, void* d_ws, size_t ws_size,
                              hipStream_t stream) {
    const float* query = (const float*)d_in[0];
    const float* wq = (const float*)d_in[1];
    const float* wk = (const float*)d_in[2];
    const float* wv = (const float*)d_in[3];
    const float* wo = (const float*)d_in[4];
    const float* Aq = (const float*)d_in[5];
    const float* Bq = (const float*)d_in[6];
    const float* Av = (const float*)d_in[7];
    const float* Bv = (const float*)d_in[8];
    float* out = (float*)d_out;

    const size_t MB = 1ull << 20;
    if (ws_size < 120 * MB) return;
    char* ws = (char*)d_ws;
    uint16_t* Xbf = (uint16_t*)(ws);                   // 16 MB
    uint16_t* Wt  = (uint16_t*)(ws + 16 * MB);         //  8 MB
    uint16_t* qkv = (uint16_t*)(ws + 24 * MB);         // 48 MB
    uint16_t* Qr  = (uint16_t*)(ws + 72 * MB);         // 16 MB
    uint16_t* Kr  = (uint16_t*)(ws + 88 * MB);         // 16 MB
    uint16_t* Vt  = (uint16_t*)(ws + 104 * MB);        // 16 MB
    uint16_t* Obuf = qkv;                              // reuse (dead after rope/vtrans)

    cast_x_kernel<<<4096, 256, 0, stream>>>(query, Xbf);
    make_wt_kernel<<<dim3(16, 16, 4), 256, 0, stream>>>(wq, wk, wv, wo, Aq, Bq, Av, Bv, Wt);
    gemm_bt_kernel<false><<<dim3(3072 / 128, M_ / 128), 256, 0, stream>>>(
        Xbf, Wt, qkv, nullptr, M_, 3072, D_);
    rope_kernel<<<16384, 256, 0, stream>>>(qkv, Qr, Kr);
    vtrans_kernel<<<dim3(T_ / 32, B_ * H_), 256, 0, stream>>>(qkv, Vt);
    attn_kernel<<<1024, 256, 0, stream>>>(Qr, Kr, Vt, Obuf);
    gemm_bt_kernel<true><<<dim3(D_ / 128, M_ / 128), 256, 0, stream>>>(
        Obuf, Wt + 3ull * D_ * D_, nullptr, out, M_, D_, D_);
}

// Round 7
// 412.674 us; speedup vs baseline: 3.8963x; 1.1418x over previous
//
#include <hip/hip_runtime.h>
#include <cstdint>

// Problem constants
#define B_  4
#define T_  2048
#define D_  1024
#define H_  16
#define DH_ 64
#define R_  8
#define M_  (B_*T_)          // 8192
#define LORA_SCALE 4.0f

typedef __attribute__((ext_vector_type(8))) short    bf16x8;
typedef __attribute__((ext_vector_type(4))) short    bf16x4;
typedef __attribute__((ext_vector_type(4))) float    f32x4;
typedef __attribute__((ext_vector_type(4))) uint32_t u32x4;

__device__ inline uint16_t f2b(float f) {             // fp32 -> bf16 RNE
    uint32_t x = __float_as_uint(f);
    return (uint16_t)((x + 0x7fffu + ((x >> 16) & 1u)) >> 16);
}
__device__ inline float b2f(uint16_t u) { return __uint_as_float(((uint32_t)u) << 16); }

__device__ __forceinline__ void gld_lds16(const uint16_t* g, uint16_t* l) {
    __builtin_amdgcn_global_load_lds(
        (const __attribute__((address_space(1))) void*)g,
        (__attribute__((address_space(3))) void*)l, 16, 0, 0);
}

// ---------------------------------------------------------------------------
// K1: cast query fp32 -> bf16   (8 elems/thread)
// ---------------------------------------------------------------------------
__global__ void cast_x_kernel(const float* __restrict__ x, uint16_t* __restrict__ out) {
    int g = blockIdx.x * 256 + threadIdx.x;
    const float4* xv = (const float4*)x;
    float4 a = xv[2 * g], b = xv[2 * g + 1];
    union { u32x4 v; uint16_t s[8]; } u;
    u.s[0] = f2b(a.x); u.s[1] = f2b(a.y); u.s[2] = f2b(a.z); u.s[3] = f2b(a.w);
    u.s[4] = f2b(b.x); u.s[5] = f2b(b.y); u.s[6] = f2b(b.z); u.s[7] = f2b(b.w);
    ((u32x4*)out)[g] = u.v;
}

// ---------------------------------------------------------------------------
// K2: build transposed bf16 weights Wt[n][k]; fold LoRA into wq/wv.
// ---------------------------------------------------------------------------
__global__ void make_wt_kernel(const float* __restrict__ wq, const float* __restrict__ wk,
                               const float* __restrict__ wv, const float* __restrict__ wo,
                               const float* __restrict__ Aq, const float* __restrict__ Bq,
                               const float* __restrict__ Av, const float* __restrict__ Bv,
                               uint16_t* __restrict__ Wt) {
    __shared__ float tile[64][65];
    int mat = blockIdx.z;
    int n0 = blockIdx.x * 64, k0 = blockIdx.y * 64;
    const float* W  = (mat == 0) ? wq : (mat == 1) ? wk : (mat == 2) ? wv : wo;
    const float* Ap = (mat == 0) ? Aq : (mat == 2) ? Av : nullptr;
    const float* Bp = (mat == 0) ? Bq : (mat == 2) ? Bv : nullptr;
    int t = threadIdx.x;
    int r = t >> 2, c0 = (t & 3) * 16;
    int k = k0 + r;
    #pragma unroll
    for (int j = 0; j < 16; j++) {
        int n = n0 + c0 + j;
        float v = W[(size_t)k * D_ + n];
        if (Ap) {
            float acc = 0.f;
            #pragma unroll
            for (int rr = 0; rr < R_; rr++) acc += Ap[k * R_ + rr] * Bp[rr * D_ + n];
            v += LORA_SCALE * acc;
        }
        tile[r][c0 + j] = v;
    }
    __syncthreads();
    int nl = t >> 2, ks = (t & 3) * 16;
    union { uint16_t s[16]; u32x4 v[2]; } uo;
    #pragma unroll
    for (int j = 0; j < 16; j++) uo.s[j] = f2b(tile[ks + j][nl]);
    uint16_t* dst = Wt + (size_t)mat * D_ * D_ + (size_t)(n0 + nl) * D_ + k0 + ks;
    *(u32x4*)&dst[0] = uo.v[0];
    *(u32x4*)&dst[8] = uo.v[1];
}

// ---------------------------------------------------------------------------
// K3/K7: C = A(MxK bf16, row-major) @ Bt(NxK bf16, row-major)^T
// ---------------------------------------------------------------------------
template <bool OUT_F32>
__global__ __launch_bounds__(256)
void gemm_bt_kernel(const uint16_t* __restrict__ A, const uint16_t* __restrict__ Bt,
                    uint16_t* __restrict__ Cb, float* __restrict__ Cf,
                    int Mdim, int Ndim, int Kdim) {
    __shared__ uint16_t At[128 * 32];
    __shared__ uint16_t Bs[128 * 32];
    int tid = threadIdx.x;
    int wave = tid >> 6, lane = tid & 63, quad = lane >> 4, l15 = lane & 15;
    int rowBase = blockIdx.y * 128, colBase = blockIdx.x * 128;
    int wRow = (wave >> 1) * 64, wCol = (wave & 1) * 64;
    int srow0 = tid >> 2, sseg0 = (tid & 3) * 8;
    int srow1 = (tid + 256) >> 2;
    f32x4 acc[4][4] = {};
    for (int kb = 0; kb < Kdim; kb += 32) {
        gld_lds16(&A [(size_t)(rowBase + srow0) * Kdim + kb + sseg0], &At[srow0 * 32 + sseg0]);
        gld_lds16(&A [(size_t)(rowBase + srow1) * Kdim + kb + sseg0], &At[srow1 * 32 + sseg0]);
        gld_lds16(&Bt[(size_t)(colBase + srow0) * Kdim + kb + sseg0], &Bs[srow0 * 32 + sseg0]);
        gld_lds16(&Bt[(size_t)(colBase + srow1) * Kdim + kb + sseg0], &Bs[srow1 * 32 + sseg0]);
        __syncthreads();
        bf16x8 af[4], bfr[4];
        #pragma unroll
        for (int m = 0; m < 4; m++) af[m]  = *(const bf16x8*)&At[(wRow + m * 16 + l15) * 32 + quad * 8];
        #pragma unroll
        for (int n = 0; n < 4; n++) bfr[n] = *(const bf16x8*)&Bs[(wCol + n * 16 + l15) * 32 + quad * 8];
        #pragma unroll
        for (int m = 0; m < 4; m++)
            #pragma unroll
            for (int n = 0; n < 4; n++)
                acc[m][n] = __builtin_amdgcn_mfma_f32_16x16x32_bf16(af[m], bfr[n], acc[m][n], 0, 0, 0);
        __syncthreads();
    }
    #pragma unroll
    for (int m = 0; m < 4; m++) {
        int row = rowBase + wRow + m * 16 + quad * 4;
        #pragma unroll
        for (int n = 0; n < 4; n++) {
            int col = colBase + wCol + n * 16 + l15;
            #pragma unroll
            for (int r = 0; r < 4; r++) {
                float v = acc[m][n][r];
                if (OUT_F32) Cf[(size_t)(row + r) * Ndim + col] = v;
                else         Cb[(size_t)(row + r) * Ndim + col] = f2b(v);
            }
        }
    }
}

// ---------------------------------------------------------------------------
// K4: RoPE on q,k; reshape (B,T,3D) -> (B,H,T,dh).
// Qr: linear (B,H,T,dh).  Kr: SWIZZLED within each 128-row tile so that a
// plain lane-ordered global_load_lds image is bank-conflict-free for MFMA
// fragment reads: 16B chunk c of row t stored at chunk c^(t&7).
// ---------------------------------------------------------------------------
__global__ void rope_kernel(const uint16_t* __restrict__ qkv,
                            uint16_t* __restrict__ Qr, uint16_t* __restrict__ Kr) {
    int g = blockIdx.x * 256 + threadIdx.x;
    int i  = g & 31;
    int t  = (g >> 5) & (T_ - 1);
    int bh = g >> 16;
    int h = bh & 15, b = bh >> 4;
    size_t rowoff = ((size_t)(b * T_ + t)) * 3072 + h * 64 + 2 * i;
    uint32_t qp = *(const uint32_t*)&qkv[rowoff];
    uint32_t kp = *(const uint32_t*)&qkv[rowoff + 1024];
    float qe = b2f((uint16_t)qp), qo = b2f((uint16_t)(qp >> 16));
    float ke = b2f((uint16_t)kp), ko = b2f((uint16_t)(kp >> 16));
    float inv = exp2f(-(float)i * (13.2877123795494f / 32.f));
    float th = (float)t * inv;
    float s = sinf(th), c = cosf(th);
    uint32_t qw = (uint32_t)f2b(qe * c - qo * s) | ((uint32_t)f2b(qe * s + qo * c) << 16);
    uint32_t kw = (uint32_t)f2b(ke * c - ko * s) | ((uint32_t)f2b(ke * s + ko * c) << 16);
    size_t o = ((size_t)bh * T_ + t) * 64 + 2 * i;
    *(uint32_t*)&Qr[o] = qw;
    int d = 2 * i;
    size_t kidx = ((size_t)bh * T_ + t) * 64 + ((((d >> 3) ^ (t & 7)) << 3) | (d & 7));
    *(uint32_t*)&Kr[kidx] = kw;
}

// ---------------------------------------------------------------------------
// K5: V -> Vt (B,H,dh,T) via LDS tile transpose.  Vt is SWIZZLED within each
// (64 d x 128 t) tile: 16B t-chunk c of d-row stored at (c&8)|((c^(d&7))&7).
// ---------------------------------------------------------------------------
__global__ void vtrans_kernel(const uint16_t* __restrict__ qkv, uint16_t* __restrict__ Vt) {
    __shared__ uint16_t tile[32][72];
    int bh = blockIdx.y, t0 = blockIdx.x * 32;
    int b = bh >> 4, h = bh & 15;
    int tid = threadIdx.x;
    int r = tid >> 3, c8 = (tid & 7) * 8;
    *(u32x4*)&tile[r][c8] =
        *(const u32x4*)&qkv[((size_t)(b * T_ + t0 + r)) * 3072 + 2048 + h * 64 + c8];
    __syncthreads();
    int d = tid >> 2, t8 = (tid & 3) * 8;
    union { uint16_t s[8]; u32x4 v; } uu;
    #pragma unroll
    for (int j = 0; j < 8; j++) uu.s[j] = tile[t8 + j][d];
    int tt = t0 + t8;
    int c  = (tt & 127) >> 3;
    int phys = (c & 8) | ((c ^ (d & 7)) & 7);
    size_t vidx = (size_t)bh * 64 * T_ + (size_t)(tt >> 7) * 8192 + d * 128 + phys * 8;
    *(u32x4*)&Vt[vidx] = uu.v;
}

// ---------------------------------------------------------------------------
// K6: causal flash attention, S^T orientation, LDS-staged K/V via
// global_load_lds with PRE-SWIZZLED global layouts (see K4/K5): the DMA is
// the exact m97 lane-ordered pattern (no staging VGPRs -> no spill), and the
// swizzle baked into Kr/Vt makes all MFMA fragment LDS reads <=2-way banked.
// Chunk=128 kpos staged once per block, shared by 4 waves (4x fewer global
// loads -- the measured limiter was ~64 cy per vector load per CU).
// P has its own padded LDS region (no aliasing). 2 barriers per chunk.
// ---------------------------------------------------------------------------
#define PSTR 136

__device__ __forceinline__ f32x4 mfma16(bf16x8 a, bf16x8 b, f32x4 c) {
    return __builtin_amdgcn_mfma_f32_16x16x32_bf16(a, b, c, 0, 0, 0);
}

template <bool MASKED>
__device__ __forceinline__ void attn_chunk_sw(
    const uint16_t* __restrict__ Kst, const uint16_t* __restrict__ Vst,
    uint16_t* __restrict__ Pw, int nact, int base_kmq,
    bf16x8 aQ0, bf16x8 aQ1, int l15, int quad,
    f32x4 (&Oacc)[4], float& mrow, float& lrow)
{
    int lx = l15 & 7;
    f32x4 sacc[8];
    #pragma unroll
    for (int n = 0; n < 8; n++) {
        if (MASKED && n >= nact) continue;
        int rowK = (n * 16 + l15) * 64;
        bf16x8 kv0 = *(const bf16x8*)&Kst[rowK + ((quad ^ lx) << 3)];
        bf16x8 kv1 = *(const bf16x8*)&Kst[rowK + (((quad + 4) ^ lx) << 3)];
        f32x4 s = {};
        s = mfma16(kv0, aQ0, s);
        s = mfma16(kv1, aQ1, s);
        sacc[n] = s;
    }
    const float SC = 0.125f * 1.44269504089f;   // 1/sqrt(64) * log2(e)
    float mx = -1e30f;
    #pragma unroll
    for (int n = 0; n < 8; n++) {
        if (MASKED && n >= nact) continue;
        #pragma unroll
        for (int r = 0; r < 4; r++) {
            float v = sacc[n][r] * SC;
            if (MASKED) {
                int kmq = base_kmq + n * 16 + quad * 4 + r;   // kpos - q
                v = (kmq > 0) ? -1e30f : v;
            }
            sacc[n][r] = v;
            mx = fmaxf(mx, v);
        }
    }
    mx = fmaxf(mx, __shfl_xor(mx, 16, 64));
    mx = fmaxf(mx, __shfl_xor(mx, 32, 64));
    float mnew = fmaxf(mrow, mx);
    float alpha = exp2f(mrow - mnew);
    float sum = 0.f;
    #pragma unroll
    for (int n = 0; n < 8; n++) {
        if (MASKED && n >= nact) continue;
        #pragma unroll
        for (int r = 0; r < 4; r++) {
            float e = exp2f(sacc[n][r] - mnew);
            sacc[n][r] = e;
            sum += e;
        }
    }
    sum += __shfl_xor(sum, 16, 64);
    sum += __shfl_xor(sum, 32, 64);
    lrow = lrow * alpha + sum;
    mrow = mnew;
    #pragma unroll
    for (int m = 0; m < 4; m++)
        #pragma unroll
        for (int r = 0; r < 4; r++) Oacc[m][r] *= alpha;
    // P^T -> own LDS slab (wave-private, no barrier needed)
    #pragma unroll
    for (int n = 0; n < 8; n++) {
        if (MASKED && n >= nact) continue;
        bf16x4 pk;
        pk[0] = (short)f2b(sacc[n][0]); pk[1] = (short)f2b(sacc[n][1]);
        pk[2] = (short)f2b(sacc[n][2]); pk[3] = (short)f2b(sacc[n][3]);
        *(bf16x4*)&Pw[l15 * PSTR + n * 16 + quad * 4] = pk;
    }
    if (MASKED && (nact & 1)) {                 // zero odd tail tile for b128 reads
        bf16x4 z = {};
        *(bf16x4*)&Pw[l15 * PSTR + nact * 16 + quad * 4] = z;
    }
    int ssact = MASKED ? ((nact + 1) >> 1) : 4;
    #pragma unroll
    for (int ss = 0; ss < 4; ss++) {
        if (MASKED && ss >= ssact) continue;
        bf16x8 bP = *(const bf16x8*)&Pw[l15 * PSTR + ss * 32 + quad * 8];
        #pragma unroll
        for (int m = 0; m < 4; m++) {
            int cl = ss * 4 + quad;
            int phys = (cl & 8) | ((cl ^ lx) & 7);
            bf16x8 aV = *(const bf16x8*)&Vst[(m * 16 + l15) * 128 + (phys << 3)];
            Oacc[m] = mfma16(aV, bP, Oacc[m]);
        }
    }
}

__global__ __launch_bounds__(256)
void attn_kernel(const uint16_t* __restrict__ Qr, const uint16_t* __restrict__ Kr,
                 const uint16_t* __restrict__ Vt, uint16_t* __restrict__ Obuf) {
    __shared__ uint16_t KLDS[128 * 64];         // 16384 B, verbatim swizzled tile
    __shared__ uint16_t VLDS[64 * 128];         // 16384 B, verbatim swizzled tile
    __shared__ uint16_t Pl[4][16 * PSTR];       // 17408 B, padded, wave-private slabs
    // XCD swizzle: bh's 16 q-blocks resident on one XCD (K/V L2-local)
    int id  = blockIdx.x;
    int xcd = id & 7, grp = id >> 3;
    int bh  = xcd * 8 + (grp & 7);
    int qx  = grp >> 3;                         // 0..15
    int b = bh >> 4, h = bh & 15;
    int tid = threadIdx.x, wave = tid >> 6, lane = tid & 63, quad = lane >> 4, l15 = lane & 15;
    const uint16_t* Qbase = Qr + (size_t)bh * T_ * 64;
    const uint16_t* Kbase = Kr + (size_t)bh * T_ * 64;
    const uint16_t* Vbase = Vt + (size_t)bh * 64 * T_;
    uint16_t* Pw = &Pl[wave][0];
    #pragma unroll
    for (int pass = 0; pass < 2; pass++) {
        int qt = pass ? (31 - qx) : qx;
        int q0w = qt * 64 + wave * 16;
        bf16x8 aQ0 = *(const bf16x8*)&Qbase[(size_t)(q0w + l15) * 64 + quad * 8];
        bf16x8 aQ1 = *(const bf16x8*)&Qbase[(size_t)(q0w + l15) * 64 + 32 + quad * 8];
        f32x4 Oacc[4] = {};
        float mrow = -1e30f, lrow = 0.f;
        int nch = (qt >> 1) + 1;
        int klim = q0w + 15;
        for (int c = 0; c < nch; c++) {
            int k0 = c * 128;
            __syncthreads();                    // (a) all waves done with prev K/V LDS
            const uint16_t* gK = Kbase + (size_t)k0 * 64;   // swizzled tile is contiguous
            const uint16_t* gV = Vbase + (size_t)k0 * 64;
            #pragma unroll
            for (int j = 0; j < 4; j++) {
                gld_lds16(gK + (tid + j * 256) * 8, &KLDS[(tid + j * 256) * 8]);
                gld_lds16(gV + (tid + j * 256) * 8, &VLDS[(tid + j * 256) * 8]);
            }
            __syncthreads();                    // (b) DMA drained + visible
            if (c == nch - 1) {
                int nact = ((klim - k0) >> 4) + 1;
                attn_chunk_sw<true>(KLDS, VLDS, Pw, nact, k0 - q0w - l15,
                                    aQ0, aQ1, l15, quad, Oacc, mrow, lrow);
            } else {
                attn_chunk_sw<false>(KLDS, VLDS, Pw, 8, 0,
                                     aQ0, aQ1, l15, quad, Oacc, mrow, lrow);
            }
        }
        // epilogue: O^T -> own P slab -> coalesced global
        float invl = 1.0f / lrow;
        float* Ow = (float*)Pw;                 // 16 q-rows x 68 f32 (272B stride)
        #pragma unroll
        for (int m = 0; m < 4; m++) {
            f32x4 o;
            #pragma unroll
            for (int r = 0; r < 4; r++) o[r] = Oacc[m][r] * invl;
            *(f32x4*)&Ow[l15 * 68 + m * 16 + quad * 4] = o;
        }
        int orow = lane >> 2, ocol = (lane & 3) * 16;
        #pragma unroll
        for (int jj = 0; jj < 4; jj++) {
            f32x4 ov = *(const f32x4*)&Ow[orow * 68 + ocol + jj * 4];
            bf16x4 ob;
            ob[0] = (short)f2b(ov[0]); ob[1] = (short)f2b(ov[1]);
            ob[2] = (short)f2b(ov[2]); ob[3] = (short)f2b(ov[3]);
            *(bf16x4*)&Obuf[((size_t)(b * T_ + qt * 64 + wave * 16 + orow)) * D_
                            + h * 64 + ocol + jj * 4] = ob;
        }
    }
}

// ---------------------------------------------------------------------------
extern "C" void kernel_launch(void* const* d_in, const int* in_sizes, int n_in,
                              void* d_out, int out_size, void* d_ws, size_t ws_size,
                              hipStream_t stream) {
    const float* query = (const float*)d_in[0];
    const float* wq = (const float*)d_in[1];
    const float* wk = (const float*)d_in[2];
    const float* wv = (const float*)d_in[3];
    const float* wo = (const float*)d_in[4];
    const float* Aq = (const float*)d_in[5];
    const float* Bq = (const float*)d_in[6];
    const float* Av = (const float*)d_in[7];
    const float* Bv = (const float*)d_in[8];
    float* out = (float*)d_out;

    const size_t MB = 1ull << 20;
    if (ws_size < 120 * MB) return;
    char* ws = (char*)d_ws;
    uint16_t* Xbf = (uint16_t*)(ws);                   // 16 MB
    uint16_t* Wt  = (uint16_t*)(ws + 16 * MB);         //  8 MB
    uint16_t* qkv = (uint16_t*)(ws + 24 * MB);         // 48 MB
    uint16_t* Qr  = (uint16_t*)(ws + 72 * MB);         // 16 MB
    uint16_t* Kr  = (uint16_t*)(ws + 88 * MB);         // 16 MB (tile-swizzled)
    uint16_t* Vt  = (uint16_t*)(ws + 104 * MB);        // 16 MB (tile-swizzled)
    uint16_t* Obuf = qkv;                              // reuse (dead after rope/vtrans)

    cast_x_kernel<<<4096, 256, 0, stream>>>(query, Xbf);
    make_wt_kernel<<<dim3(16, 16, 4), 256, 0, stream>>>(wq, wk, wv, wo, Aq, Bq, Av, Bv, Wt);
    gemm_bt_kernel<false><<<dim3(3072 / 128, M_ / 128), 256, 0, stream>>>(
        Xbf, Wt, qkv, nullptr, M_, 3072, D_);
    rope_kernel<<<16384, 256, 0, stream>>>(qkv, Qr, Kr);
    vtrans_kernel<<<dim3(T_ / 32, B_ * H_), 256, 0, stream>>>(qkv, Vt);
    attn_kernel<<<1024, 256, 0, stream>>>(Qr, Kr, Vt, Obuf);
    gemm_bt_kernel<true><<<dim3(D_ / 128, M_ / 128), 256, 0, stream>>>(
        Obuf, Wt + 3ull * D_ * D_, nullptr, out, M_, D_, D_);
}